// Round 3
// baseline (149.675 us; speedup 1.0000x reference)
//
#include <hip/hip_runtime.h>

#define KDIM 64
#define VDIM 64
#define MDIM 2048
#define BDIM 512
#define INDIM 512
#define HDIM 192           // 2K+V
#define CIN 768            // IN + 2K + 2V
#define O_SIZE (BDIM*HDIM) // 98304

// ---------- K1: o = [x, relu(h), content] @ W^T + bias ----------
__global__ __launch_bounds__(256)
void gemm_kernel(const float* __restrict__ x, const float* __restrict__ hidden,
                 const float* __restrict__ content, const float* __restrict__ W,
                 const float* __restrict__ bias, float* __restrict__ out)
{
    const int b   = blockIdx.x;
    const int tid = threadIdx.x;
    __shared__ __align__(16) float inp[CIN];

    inp[tid]       = x[(size_t)b*INDIM + tid];
    inp[256 + tid] = x[(size_t)b*INDIM + 256 + tid];
    if (tid < HDIM) inp[INDIM + tid] = fmaxf(hidden[(size_t)b*HDIM + tid], 0.f);
    if (tid < VDIM) inp[INDIM + HDIM + tid] = content[(size_t)b*VDIM + tid];
    __syncthreads();

    if (tid < HDIM) {
        const float4* w4 = reinterpret_cast<const float4*>(W) + (size_t)tid * (CIN/4);
        const float4* i4 = reinterpret_cast<const float4*>(inp);
        float ax = 0.f, ay = 0.f, az = 0.f, aw = 0.f;
        #pragma unroll
        for (int r = 0; r < CIN/4; r += 8) {
            float4 wr[8];
            #pragma unroll
            for (int u = 0; u < 8; ++u) wr[u] = w4[r + u];
            #pragma unroll
            for (int u = 0; u < 8; ++u) {
                float4 v = i4[r + u];
                ax = fmaf(wr[u].x, v.x, ax);
                ay = fmaf(wr[u].y, v.y, ay);
                az = fmaf(wr[u].z, v.z, az);
                aw = fmaf(wr[u].w, v.w, aw);
            }
        }
        out[(size_t)b*HDIM + tid] = (ax + ay) + (az + aw) + bias[tid];
    }
}

// ---------- K2: scores[b,m] = sum_k key_mem[b,k,m] * q[b,k] ----------
// grid = BDIM*4 blocks x 256 thr; block covers 512 m's; thread owns a float2.
__global__ __launch_bounds__(256, 8)
void scores_kernel(const float* __restrict__ key_mem,
                   const float* __restrict__ o,      // q = o[:, :64]
                   float* __restrict__ scores)
{
    const int bid  = blockIdx.x;
    const int b    = bid >> 2;
    const int mb   = (bid & 3) * 512;
    const int tid  = threadIdx.x;

    __shared__ float q[KDIM];
    if (tid < KDIM) q[tid] = o[(size_t)b*HDIM + tid];
    __syncthreads();

    const float2* km2 = reinterpret_cast<const float2*>(key_mem)
                        + ((size_t)b*KDIM*MDIM + mb)/2 + tid;
    float sx = 0.f, sy = 0.f;
    #pragma unroll
    for (int k0 = 0; k0 < KDIM; k0 += 8) {
        float2 kk[8];
        #pragma unroll
        for (int u = 0; u < 8; ++u)
            kk[u] = km2[(size_t)(k0 + u) * (MDIM/2)];
        #pragma unroll
        for (int u = 0; u < 8; ++u) {
            float qk = q[k0 + u];
            sx = fmaf(qk, kk[u].x, sx);
            sy = fmaf(qk, kk[u].y, sy);
        }
    }
    reinterpret_cast<float2*>(scores)[(size_t)b*(MDIM/2) + mb/2 + tid]
        = make_float2(sx, sy);
}

// ---------- K3: in-place softmax over each row of scores ----------
__global__ __launch_bounds__(256)
void softmax_kernel(float* __restrict__ scores)
{
    const int b    = blockIdx.x;
    const int tid  = threadIdx.x;
    const int lane = tid & 63;
    const int wid  = tid >> 6;
    __shared__ float red[4];

    float4* row4 = reinterpret_cast<float4*>(scores + (size_t)b*MDIM);
    float4 s0 = row4[tid];
    float4 s1 = row4[256 + tid];

    float mx = fmaxf(fmaxf(fmaxf(s0.x, s0.y), fmaxf(s0.z, s0.w)),
                     fmaxf(fmaxf(s1.x, s1.y), fmaxf(s1.z, s1.w)));
    #pragma unroll
    for (int off = 32; off >= 1; off >>= 1) mx = fmaxf(mx, __shfl_xor(mx, off));
    if (lane == 0) red[wid] = mx;
    __syncthreads();
    float m_all = fmaxf(fmaxf(red[0], red[1]), fmaxf(red[2], red[3]));

    float4 e0, e1;
    e0.x = __expf(s0.x - m_all); e0.y = __expf(s0.y - m_all);
    e0.z = __expf(s0.z - m_all); e0.w = __expf(s0.w - m_all);
    e1.x = __expf(s1.x - m_all); e1.y = __expf(s1.y - m_all);
    e1.z = __expf(s1.z - m_all); e1.w = __expf(s1.w - m_all);
    float sum = (e0.x + e0.y) + (e0.z + e0.w) + (e1.x + e1.y) + (e1.z + e1.w);
    #pragma unroll
    for (int off = 32; off >= 1; off >>= 1) sum += __shfl_xor(sum, off);
    __syncthreads();
    if (lane == 0) red[wid] = sum;
    __syncthreads();
    float inv = 1.0f / (red[0] + red[1] + red[2] + red[3]);

    e0.x *= inv; e0.y *= inv; e0.z *= inv; e0.w *= inv;
    e1.x *= inv; e1.y *= inv; e1.z *= inv; e1.w *= inv;
    row4[tid]       = e0;
    row4[256 + tid] = e1;
}

// ---------- K4: content_new[b,v] = sum_m value_mem[b,v,m] * attn[b,m] ----------
// one wave per (b,v); grid = BDIM*VDIM/4 blocks x 256 thr.
__global__ __launch_bounds__(256, 4)
void pv_kernel(const float* __restrict__ value_mem,
               const float* __restrict__ attn,
               float* __restrict__ out)
{
    const int tid  = threadIdx.x;
    const int lane = tid & 63;
    const int wid  = tid >> 6;
    const int gwid = blockIdx.x * 4 + wid;
    const int b    = gwid >> 6;
    const int v    = gwid & 63;

    const float4* vm4 = reinterpret_cast<const float4*>(value_mem)
                        + ((size_t)b*VDIM + v) * (MDIM/4);
    const float4* a4  = reinterpret_cast<const float4*>(attn) + (size_t)b*(MDIM/4);

    float4 vv[8], aa[8];
    #pragma unroll
    for (int i = 0; i < 8; ++i) vv[i] = vm4[i*64 + lane];
    #pragma unroll
    for (int i = 0; i < 8; ++i) aa[i] = a4[i*64 + lane];

    float px = 0.f, py = 0.f, pz = 0.f, pw = 0.f;
    #pragma unroll
    for (int i = 0; i < 8; ++i) {
        px = fmaf(vv[i].x, aa[i].x, px);
        py = fmaf(vv[i].y, aa[i].y, py);
        pz = fmaf(vv[i].z, aa[i].z, pz);
        pw = fmaf(vv[i].w, aa[i].w, pw);
    }
    float p = (px + py) + (pz + pw);
    #pragma unroll
    for (int off = 32; off >= 1; off >>= 1) p += __shfl_xor(p, off);
    if (lane == 0) out[O_SIZE + (size_t)b*VDIM + v] = p;
}

extern "C" void kernel_launch(void* const* d_in, const int* in_sizes, int n_in,
                              void* d_out, int out_size, void* d_ws, size_t ws_size,
                              hipStream_t stream) {
    const float* x         = (const float*)d_in[0];
    const float* hidden    = (const float*)d_in[1];
    const float* content   = (const float*)d_in[2];
    const float* key_mem   = (const float*)d_in[3];
    const float* value_mem = (const float*)d_in[4];
    const float* W         = (const float*)d_in[5];
    const float* bias      = (const float*)d_in[6];
    float* out    = (float*)d_out;
    float* scores = (float*)d_ws;   // BDIM*MDIM floats = 4 MB

    gemm_kernel   <<<dim3(BDIM),        dim3(256), 0, stream>>>(x, hidden, content, W, bias, out);
    scores_kernel <<<dim3(BDIM*4),      dim3(256), 0, stream>>>(key_mem, out, scores);
    softmax_kernel<<<dim3(BDIM),        dim3(256), 0, stream>>>(scores);
    pv_kernel     <<<dim3(BDIM*VDIM/4), dim3(256), 0, stream>>>(value_mem, scores, out);
}